// Round 10
// baseline (230.539 us; speedup 1.0000x reference)
//
#include <hip/hip_runtime.h>
#include <stdint.h>

// MoE: B=4 T=2048 D=512 F=1024 E=8 top_k=2. Inputs/output f32; internals bf16.
#define N_TOK 8192
#define D_DIM 512
#define F_DIM 1024
#define E_NUM 8
#define M_SLOTS (N_TOK * 2)

typedef __bf16 bf16x8 __attribute__((ext_vector_type(8)));
typedef float f32x4 __attribute__((ext_vector_type(4)));

__device__ __forceinline__ ushort f2b(float f) {  // f32 -> bf16 rne
    union { float f; unsigned u; } v; v.f = f;
    unsigned r = v.u + 0x7fffu + ((v.u >> 16) & 1u);
    return (ushort)(r >> 16);
}
__device__ __forceinline__ float b2f(ushort u) {
    union { unsigned i; float f; } v; v.i = ((unsigned)u) << 16; return v.f;
}
__device__ __forceinline__ void gload16(const void* g, void* l) {
    // async global->LDS, 16B/lane; LDS dest is wave-uniform base + lane*16
    __builtin_amdgcn_global_load_lds(
        (const __attribute__((address_space(1))) unsigned int*)g,
        (__attribute__((address_space(3))) unsigned int*)l, 16, 0, 0);
}

__global__ void init_k(int* cnt) {
    if (threadIdx.x < 16) cnt[threadIdx.x] = 0;
}

// ------- 64x64 tiled transpose + f32->bf16 convert, per expert (blockIdx.z) --
__global__ __launch_bounds__(256) void transpose_k(const float* __restrict__ in,
                                                   ushort* __restrict__ out,
                                                   int R, int C) {
    __shared__ ushort tile[64][66];
    int e = blockIdx.z;
    const float* src = in + (size_t)e * R * C;
    ushort* dst = out + (size_t)e * R * C;
    int c0 = blockIdx.x * 64, r0 = blockIdx.y * 64;
    for (int i = threadIdx.x; i < 64 * 64; i += 256) {
        int r = i >> 6, c = i & 63;
        tile[r][c] = f2b(src[(size_t)(r0 + r) * C + c0 + c]);
    }
    __syncthreads();
    for (int i = threadIdx.x; i < 64 * 64; i += 256) {
        int c = i >> 6, r = i & 63;
        dst[(size_t)(c0 + c) * R + r0 + r] = tile[r][c];
    }
}

// ------ logits: one wave per token, f32 math, NO atomics; fuses x->bf16 -----
__global__ __launch_bounds__(256) void logits_k(const float* __restrict__ x,
                                                const float* __restrict__ rw,
                                                const float* __restrict__ rb,
                                                ushort* __restrict__ x_bf,
                                                int* __restrict__ tok_e,
                                                float* __restrict__ tok_w) {
    int lane = threadIdx.x & 63, wv = threadIdx.x >> 6;
    int t = blockIdx.x * 4 + wv;
    float4 xa = *(const float4*)(x + (size_t)t * D_DIM + lane * 8);
    float4 xb = *(const float4*)(x + (size_t)t * D_DIM + lane * 8 + 4);
    ushort u[8] = {f2b(xa.x), f2b(xa.y), f2b(xa.z), f2b(xa.w),
                   f2b(xb.x), f2b(xb.y), f2b(xb.z), f2b(xb.w)};
    *(uint4*)(x_bf + (size_t)t * D_DIM + lane * 8) = *(const uint4*)u;

    float acc[E_NUM];
#pragma unroll
    for (int e = 0; e < E_NUM; ++e) {
        float4 wa = *(const float4*)(rw + (size_t)e * D_DIM + lane * 8);
        float4 wb = *(const float4*)(rw + (size_t)e * D_DIM + lane * 8 + 4);
        float s = xa.x * wa.x + xa.y * wa.y + xa.z * wa.z + xa.w * wa.w +
                  xb.x * wb.x + xb.y * wb.y + xb.z * wb.z + xb.w * wb.w;
#pragma unroll
        for (int o = 32; o > 0; o >>= 1) s += __shfl_xor(s, o, 64);
        acc[e] = s;
    }
    if (lane == 0) {
        float l[E_NUM];
#pragma unroll
        for (int e = 0; e < E_NUM; ++e) l[e] = acc[e] + rb[e];
        int e0 = 0;
#pragma unroll
        for (int e = 1; e < E_NUM; ++e) if (l[e] > l[e0]) e0 = e;
        int e1 = (e0 == 0) ? 1 : 0;
#pragma unroll
        for (int e = 0; e < E_NUM; ++e) if (e != e0 && l[e] > l[e1]) e1 = e;
        float p1 = __expf(l[e1] - l[e0]);
        float w0 = 1.f / (1.f + p1), w1 = p1 / (1.f + p1);
        tok_e[2 * t] = e0;  tok_e[2 * t + 1] = e1;
        tok_w[2 * t] = w0;  tok_w[2 * t + 1] = w1;
    }
}

// ------ assign: per-block LDS histogram -> 8 global atomics per block -------
__global__ __launch_bounds__(256) void assign_k(const int* __restrict__ tok_e,
                                                int* __restrict__ cnt,
                                                int* __restrict__ rank) {
    __shared__ int lcnt[E_NUM], lbase[E_NUM];
    int tid = threadIdx.x;
    int i = blockIdx.x * 256 + tid;
    if (tid < E_NUM) lcnt[tid] = 0;
    __syncthreads();
    int e = tok_e[i];
    int intra = atomicAdd(&lcnt[e], 1);
    __syncthreads();
    if (tid < E_NUM) lbase[tid] = atomicAdd(&cnt[tid], lcnt[tid]);
    __syncthreads();
    rank[i] = lbase[e] + intra;
}

__global__ void prefix_k(const int* __restrict__ cnt, int* __restrict__ ebase) {
    if (threadIdx.x == 0) {
        int s = 0;
        for (int e = 0; e < E_NUM; ++e) { ebase[e] = s; s += cnt[e]; }
        ebase[E_NUM] = s;
    }
}

__global__ __launch_bounds__(256) void scatter_k(const int* __restrict__ tok_e,
                                                 const int* __restrict__ rank,
                                                 const int* __restrict__ ebase,
                                                 int* __restrict__ row_token,
                                                 int* __restrict__ tok_pos) {
    int i = blockIdx.x * 256 + threadIdx.x;  // slot index
    int pos = ebase[tok_e[i]] + rank[i];
    row_token[pos] = i >> 1;
    tok_pos[i] = pos;
}

// ---------------- GEMM1: h = silu(x@Wg) * (x@Wu), grouped by expert ----------
// BK=32, global_load_lds, row-paired 128 B LDS lines (round-8 0-conflict
// algebra): line rp holds rows {2rp, 2rp+1}; slot s holds logical position
// lp = s ^ (rp&7) -> row 2rp+(lp>>2), k-quarter lp&3. Frag-read slot is the
// pure lane function s = (4*(m&1)+q) ^ ((m>>1)&7).
__global__ __launch_bounds__(256, 4) void gemm1_k(const ushort* __restrict__ x,
                                                  const ushort* __restrict__ wgu_t,
                                                  const int* __restrict__ ebase,
                                                  const int* __restrict__ row_token,
                                                  ushort* __restrict__ h) {
    int e = blockIdx.z;
    int base = ebase[e];
    int cnt = ebase[e + 1] - base;
    int tile0 = blockIdx.y * 128;
    if (tile0 >= cnt) return;
    int c0 = blockIdx.x * 64;            // h-col tile (64 cols)

    __shared__ ushort smem[128 * 32 + 128 * 32];  // 16 KB: A | B(64 gate+64 up)
    ushort* lds_a = smem;
    ushort* lds_b = smem + 128 * 32;

    int tid = threadIdx.x;
    int lane = tid & 63, wv = tid >> 6;
    int wr = wv >> 1, wc = wv & 1;

    // staging: chunk c -> line rp=c>>3, slot s=c&7; content row/quarter per lp
    const ushort* asrc[2];
    const ushort* bsrc[2];
#pragma unroll
    for (int i = 0; i < 2; ++i) {
        int c = tid + i * 256;
        int rp = c >> 3, s = c & 7;
        int lp = s ^ (rp & 7);
        int row = 2 * rp + (lp >> 2);            // 0..127
        int q = lp & 3;
        int r = tile0 + row;
        r = (r < cnt) ? r : (cnt - 1);
        int tok = row_token[base + r];
        asrc[i] = x + (size_t)tok * D_DIM + q * 8;
        int gc = (row < 64) ? (c0 + row) : (F_DIM + c0 + row - 64);
        bsrc[i] = wgu_t + ((size_t)e * (2 * F_DIM) + gc) * D_DIM + q * 8;
    }

    f32x4 accg[4][2], accu[4][2];
#pragma unroll
    for (int a = 0; a < 4; ++a)
#pragma unroll
        for (int b = 0; b < 2; ++b) {
            accg[a][b] = (f32x4){0.f, 0.f, 0.f, 0.f};
            accu[a][b] = (f32x4){0.f, 0.f, 0.f, 0.f};
        }

    int q = lane >> 4, m = lane & 15;
    int mh = m >> 1;
    int sl = (4 * (m & 1) + q) ^ (mh & 7);       // phys slot, lane-only
    int soff = sl * 8;

    for (int k0 = 0; k0 < D_DIM; k0 += 32) {
        __syncthreads();
#pragma unroll
        for (int i = 0; i < 2; ++i) {
            int c = tid + i * 256;
            gload16(asrc[i] + k0, lds_a + (size_t)c * 8);
            gload16(bsrc[i] + k0, lds_b + (size_t)c * 8);
        }
        __syncthreads();   // vmcnt(0) drain -> LDS populated

        bf16x8 af[4], bg[2], bu[2];
#pragma unroll
        for (int mt = 0; mt < 4; ++mt)
            af[mt] = *(const bf16x8*)(lds_a + (wr * 32 + mt * 8 + mh) * 64 + soff);
#pragma unroll
        for (int nt = 0; nt < 2; ++nt) {
            bg[nt] = *(const bf16x8*)(lds_b + (wc * 16 + nt * 8 + mh) * 64 + soff);
            bu[nt] = *(const bf16x8*)(lds_b + (32 + wc * 16 + nt * 8 + mh) * 64 + soff);
        }
#pragma unroll
        for (int mt = 0; mt < 4; ++mt)
#pragma unroll
            for (int nt = 0; nt < 2; ++nt) {
                accg[mt][nt] = __builtin_amdgcn_mfma_f32_16x16x32_bf16(af[mt], bg[nt], accg[mt][nt], 0, 0, 0);
                accu[mt][nt] = __builtin_amdgcn_mfma_f32_16x16x32_bf16(af[mt], bu[nt], accu[mt][nt], 0, 0, 0);
            }
    }

    // ---- epilogue: silu*up -> LDS stage [32][68] -> coalesced 16B stores ----
    ushort* stg = smem;
    int col = m;
    __syncthreads();
#pragma unroll
    for (int mt = 0; mt < 4; ++mt) {
#pragma unroll
        for (int nt = 0; nt < 2; ++nt) {
            int sc = wc * 32 + nt * 16 + col;
#pragma unroll
            for (int r4 = 0; r4 < 4; ++r4) {
                int sr = wr * 16 + q * 4 + r4;
                float g = accg[mt][nt][r4];
                float u = accu[mt][nt][r4];
                stg[sr * 68 + sc] = f2b((g / (1.f + __expf(-g))) * u);
            }
        }
        __syncthreads();
        {
            int sr = tid >> 3;
            int coff = (tid & 7) * 8;
            int grow = tile0 + (sr >> 4) * 64 + mt * 16 + (sr & 15);
            if (grow < cnt)
                *(uint4*)(h + (size_t)(base + grow) * F_DIM + c0 + coff) =
                    *(const uint4*)(stg + sr * 68 + coff);
        }
        __syncthreads();
    }
}

// -------- GEMM2: slot = h @ Wd (bf16); BK=32, row-paired swizzled lines -----
__global__ __launch_bounds__(256, 4) void gemm2_k(const ushort* __restrict__ h,
                                                  const ushort* __restrict__ wd_t,
                                                  const int* __restrict__ ebase,
                                                  ushort* __restrict__ slot) {
    int e = blockIdx.z;
    int base = ebase[e];
    int cnt = ebase[e + 1] - base;
    int tile0 = blockIdx.y * 128;
    if (tile0 >= cnt) return;
    int c0 = blockIdx.x * 128;

    __shared__ ushort smem[128 * 32 + 128 * 32];  // 16 KB
    ushort* lds_a = smem;
    ushort* lds_b = smem + 128 * 32;

    int tid = threadIdx.x;
    int lane = tid & 63, wv = tid >> 6;
    int wr = wv >> 1, wc = wv & 1;

    const ushort* asrc[2]; const ushort* bsrc[2];
#pragma unroll
    for (int i = 0; i < 2; ++i) {
        int c = tid + i * 256;
        int rp = c >> 3, s = c & 7;
        int lp = s ^ (rp & 7);
        int row = 2 * rp + (lp >> 2);
        int q = lp & 3;
        int r = tile0 + row;
        r = (r < cnt) ? r : (cnt - 1);
        asrc[i] = h + (size_t)(base + r) * F_DIM + q * 8;
        bsrc[i] = wd_t + ((size_t)e * D_DIM + c0 + row) * F_DIM + q * 8;
    }

    f32x4 acc[4][4];
#pragma unroll
    for (int a = 0; a < 4; ++a)
#pragma unroll
        for (int b = 0; b < 4; ++b) acc[a][b] = (f32x4){0.f, 0.f, 0.f, 0.f};

    int q = lane >> 4, m = lane & 15;
    int mh = m >> 1;
    int sl = (4 * (m & 1) + q) ^ (mh & 7);
    int soff = sl * 8;

    for (int k0 = 0; k0 < F_DIM; k0 += 32) {
        __syncthreads();
#pragma unroll
        for (int i = 0; i < 2; ++i) {
            int c = tid + i * 256;
            gload16(asrc[i] + k0, lds_a + (size_t)c * 8);
            gload16(bsrc[i] + k0, lds_b + (size_t)c * 8);
        }
        __syncthreads();

        bf16x8 af[4], bb[4];
#pragma unroll
        for (int mt = 0; mt < 4; ++mt)
            af[mt] = *(const bf16x8*)(lds_a + (wr * 32 + mt * 8 + mh) * 64 + soff);
#pragma unroll
        for (int nt = 0; nt < 4; ++nt)
            bb[nt] = *(const bf16x8*)(lds_b + (wc * 32 + nt * 8 + mh) * 64 + soff);
#pragma unroll
        for (int mt = 0; mt < 4; ++mt)
#pragma unroll
            for (int nt = 0; nt < 4; ++nt)
                acc[mt][nt] = __builtin_amdgcn_mfma_f32_16x16x32_bf16(af[mt], bb[nt], acc[mt][nt], 0, 0, 0);
    }

    // epilogue: stage [32][132] -> coalesced bf16 slot rows
    ushort* stg = smem;
    int col = m;
    __syncthreads();
#pragma unroll
    for (int mt = 0; mt < 4; ++mt) {
#pragma unroll
        for (int nt = 0; nt < 4; ++nt) {
            int scol = wc * 64 + nt * 16 + col;
#pragma unroll
            for (int r4 = 0; r4 < 4; ++r4) {
                int sr = wr * 16 + q * 4 + r4;
                stg[sr * 132 + scol] = f2b(acc[mt][nt][r4]);
            }
        }
        __syncthreads();
#pragma unroll
        for (int i = 0; i < 2; ++i) {
            int c = tid + i * 256;
            int sr = c >> 4;
            int coff = (c & 15) * 8;
            int grow = tile0 + (sr >> 4) * 64 + mt * 16 + (sr & 15);
            if (grow < cnt)
                *(uint4*)(slot + (size_t)(base + grow) * D_DIM + c0 + coff) =
                    *(const uint4*)(stg + sr * 132 + coff);
        }
        __syncthreads();
    }
}

// ------ combine: out[t] = w0*slot[p0] + w1*slot[p1]  (wave per token) -------
__global__ __launch_bounds__(256) void combine_k(const ushort* __restrict__ slot,
                                                 const int* __restrict__ tok_pos,
                                                 const float* __restrict__ tok_w,
                                                 float* __restrict__ out) {
    int lane = threadIdx.x & 63, wv = threadIdx.x >> 6;
    int t = blockIdx.x * 4 + wv;
    int p0 = tok_pos[2 * t], p1 = tok_pos[2 * t + 1];
    float w0 = tok_w[2 * t], w1 = tok_w[2 * t + 1];
    uint4 s0 = *(const uint4*)(slot + (size_t)p0 * D_DIM + lane * 8);
    uint4 s1 = *(const uint4*)(slot + (size_t)p1 * D_DIM + lane * 8);
    const ushort* a = (const ushort*)&s0;
    const ushort* b = (const ushort*)&s1;
    float o[8];
#pragma unroll
    for (int j = 0; j < 8; ++j) o[j] = w0 * b2f(a[j]) + w1 * b2f(b[j]);
    float* dst = out + (size_t)t * D_DIM + lane * 8;
    *(float4*)dst = (float4){o[0], o[1], o[2], o[3]};
    *(float4*)(dst + 4) = (float4){o[4], o[5], o[6], o[7]};
}

extern "C" void kernel_launch(void* const* d_in, const int* in_sizes, int n_in,
                              void* d_out, int out_size, void* d_ws, size_t ws_size,
                              hipStream_t stream) {
    const float* x   = (const float*)d_in[0];
    const float* rw  = (const float*)d_in[1];
    const float* rb  = (const float*)d_in[2];
    const float* wgu = (const float*)d_in[3];
    const float* wd  = (const float*)d_in[4];
    float* out = (float*)d_out;

    char* ws = (char*)d_ws;
    size_t off = 0;
    auto alloc = [&](size_t bytes) -> void* {
        void* p = ws + off;
        off += (bytes + 255) & ~(size_t)255;
        return p;
    };
    ushort* wgu_t     = (ushort*)alloc((size_t)E_NUM * 2 * F_DIM * D_DIM * 2);  // 16.8 MB
    ushort* wd_t      = (ushort*)alloc((size_t)E_NUM * D_DIM * F_DIM * 2);      //  8.4 MB
    ushort* x_bf      = (ushort*)alloc((size_t)N_TOK * D_DIM * 2);              //  8.4 MB
    ushort* hbuf      = (ushort*)alloc((size_t)M_SLOTS * F_DIM * 2);            // 33.6 MB
    ushort* slot      = (ushort*)alloc((size_t)M_SLOTS * D_DIM * 2);            // 16.8 MB
    int*    row_token = (int*)alloc(M_SLOTS * 4);
    int*    tok_e     = (int*)alloc(M_SLOTS * 4);
    int*    rankbuf   = (int*)alloc(M_SLOTS * 4);
    float*  tok_w     = (float*)alloc(M_SLOTS * 4);
    int*    tok_pos   = (int*)alloc(M_SLOTS * 4);
    int*    cnt       = (int*)alloc(64);
    int*    ebase     = (int*)alloc(64);

    init_k<<<1, 64, 0, stream>>>(cnt);
    transpose_k<<<dim3(2 * F_DIM / 64, D_DIM / 64, E_NUM), 256, 0, stream>>>(wgu, wgu_t, D_DIM, 2 * F_DIM);
    transpose_k<<<dim3(D_DIM / 64, F_DIM / 64, E_NUM), 256, 0, stream>>>(wd, wd_t, F_DIM, D_DIM);
    logits_k<<<N_TOK / 4, 256, 0, stream>>>(x, rw, rb, x_bf, tok_e, tok_w);
    assign_k<<<M_SLOTS / 256, 256, 0, stream>>>(tok_e, cnt, rankbuf);
    prefix_k<<<1, 64, 0, stream>>>(cnt, ebase);
    scatter_k<<<M_SLOTS / 256, 256, 0, stream>>>(tok_e, rankbuf, ebase, row_token, tok_pos);
    gemm1_k<<<dim3(16, 32, E_NUM), 256, 0, stream>>>(x_bf, wgu_t, ebase, row_token, hbuf);
    gemm2_k<<<dim3(4, 32, E_NUM), 256, 0, stream>>>(hbuf, wd_t, ebase, slot);
    combine_k<<<N_TOK / 4, 256, 0, stream>>>(slot, tok_pos, tok_w, out);
}

// Round 11
// 227.178 us; speedup vs baseline: 1.0148x; 1.0148x over previous
//
#include <hip/hip_runtime.h>
#include <stdint.h>

// MoE: B=4 T=2048 D=512 F=1024 E=8 top_k=2. Inputs/output f32; internals bf16.
#define N_TOK 8192
#define D_DIM 512
#define F_DIM 1024
#define E_NUM 8
#define M_SLOTS (N_TOK * 2)

typedef __bf16 bf16x8 __attribute__((ext_vector_type(8)));
typedef float f32x4 __attribute__((ext_vector_type(4)));

__device__ __forceinline__ ushort f2b(float f) {  // f32 -> bf16 rne
    union { float f; unsigned u; } v; v.f = f;
    unsigned r = v.u + 0x7fffu + ((v.u >> 16) & 1u);
    return (ushort)(r >> 16);
}
__device__ __forceinline__ float b2f(ushort u) {
    union { unsigned i; float f; } v; v.i = ((unsigned)u) << 16; return v.f;
}
__device__ __forceinline__ void gload16(const void* g, void* l) {
    // async global->LDS, 16B/lane; LDS dest is wave-uniform base + lane*16
    __builtin_amdgcn_global_load_lds(
        (const __attribute__((address_space(1))) unsigned int*)g,
        (__attribute__((address_space(3))) unsigned int*)l, 16, 0, 0);
}

// ------- 64x64 tiled transpose + f32->bf16, fully vectorized ----------------
// load: 16B/lane float4; store: 16B/lane uint4 (8 rows packed per store)
__global__ __launch_bounds__(256) void transpose_k(const float* __restrict__ in,
                                                   ushort* __restrict__ out,
                                                   int R, int C) {
    __shared__ ushort tile[64][65];  // +1 pad: column reads spread banks
    int e = blockIdx.z;
    const float* src = in + (size_t)e * R * C;
    ushort* dst = out + (size_t)e * R * C;
    int c0 = blockIdx.x * 64, r0 = blockIdx.y * 64;
#pragma unroll
    for (int i = 0; i < 4; ++i) {                  // 1024 float4 chunks
        int ch = threadIdx.x + i * 256;
        int row = ch >> 4, pos = ch & 15;
        float4 v = *(const float4*)(src + (size_t)(r0 + row) * C + c0 + pos * 4);
        tile[row][pos * 4 + 0] = f2b(v.x);
        tile[row][pos * 4 + 1] = f2b(v.y);
        tile[row][pos * 4 + 2] = f2b(v.z);
        tile[row][pos * 4 + 3] = f2b(v.w);
    }
    __syncthreads();
#pragma unroll
    for (int i = 0; i < 2; ++i) {                  // 512 uint4 chunks
        int ch = threadIdx.x + i * 256;
        int ocol = ch >> 3, rb = ch & 7;
        ushort tmp[8];
#pragma unroll
        for (int j = 0; j < 8; ++j) tmp[j] = tile[rb * 8 + j][ocol];
        *(uint4*)(dst + (size_t)(c0 + ocol) * R + r0 + rb * 8) = *(const uint4*)tmp;
    }
}

// ------ logits: one wave per token, f32 math; fuses x->bf16 + cnt zeroing ---
__global__ __launch_bounds__(256) void logits_k(const float* __restrict__ x,
                                                const float* __restrict__ rw,
                                                const float* __restrict__ rb,
                                                ushort* __restrict__ x_bf,
                                                int* __restrict__ tok_e,
                                                float* __restrict__ tok_w,
                                                int* __restrict__ cnt) {
    if (blockIdx.x == 0 && threadIdx.x < 16) cnt[threadIdx.x] = 0;
    int lane = threadIdx.x & 63, wv = threadIdx.x >> 6;
    int t = blockIdx.x * 4 + wv;
    float4 xa = *(const float4*)(x + (size_t)t * D_DIM + lane * 8);
    float4 xb = *(const float4*)(x + (size_t)t * D_DIM + lane * 8 + 4);
    ushort u[8] = {f2b(xa.x), f2b(xa.y), f2b(xa.z), f2b(xa.w),
                   f2b(xb.x), f2b(xb.y), f2b(xb.z), f2b(xb.w)};
    *(uint4*)(x_bf + (size_t)t * D_DIM + lane * 8) = *(const uint4*)u;

    float acc[E_NUM];
#pragma unroll
    for (int e = 0; e < E_NUM; ++e) {
        float4 wa = *(const float4*)(rw + (size_t)e * D_DIM + lane * 8);
        float4 wb = *(const float4*)(rw + (size_t)e * D_DIM + lane * 8 + 4);
        float s = xa.x * wa.x + xa.y * wa.y + xa.z * wa.z + xa.w * wa.w +
                  xb.x * wb.x + xb.y * wb.y + xb.z * wb.z + xb.w * wb.w;
#pragma unroll
        for (int o = 32; o > 0; o >>= 1) s += __shfl_xor(s, o, 64);
        acc[e] = s;
    }
    if (lane == 0) {
        float l[E_NUM];
#pragma unroll
        for (int e = 0; e < E_NUM; ++e) l[e] = acc[e] + rb[e];
        int e0 = 0;
#pragma unroll
        for (int e = 1; e < E_NUM; ++e) if (l[e] > l[e0]) e0 = e;
        int e1 = (e0 == 0) ? 1 : 0;
#pragma unroll
        for (int e = 0; e < E_NUM; ++e) if (e != e0 && l[e] > l[e1]) e1 = e;
        float p1 = __expf(l[e1] - l[e0]);
        float w0 = 1.f / (1.f + p1), w1 = p1 / (1.f + p1);
        tok_e[2 * t] = e0;  tok_e[2 * t + 1] = e1;
        tok_w[2 * t] = w0;  tok_w[2 * t + 1] = w1;
    }
}

// ------ assign: per-block LDS histogram -> 8 global atomics per block -------
__global__ __launch_bounds__(256) void assign_k(const int* __restrict__ tok_e,
                                                int* __restrict__ cnt,
                                                int* __restrict__ rank) {
    __shared__ int lcnt[E_NUM], lbase[E_NUM];
    int tid = threadIdx.x;
    int i = blockIdx.x * 256 + tid;
    if (tid < E_NUM) lcnt[tid] = 0;
    __syncthreads();
    int e = tok_e[i];
    int intra = atomicAdd(&lcnt[e], 1);
    __syncthreads();
    if (tid < E_NUM) lbase[tid] = atomicAdd(&cnt[tid], lcnt[tid]);
    __syncthreads();
    rank[i] = lbase[e] + intra;
}

__global__ void prefix_k(const int* __restrict__ cnt, int* __restrict__ ebase) {
    if (threadIdx.x == 0) {
        int s = 0;
        for (int e = 0; e < E_NUM; ++e) { ebase[e] = s; s += cnt[e]; }
        ebase[E_NUM] = s;
    }
}

__global__ __launch_bounds__(256) void scatter_k(const int* __restrict__ tok_e,
                                                 const int* __restrict__ rank,
                                                 const int* __restrict__ ebase,
                                                 int* __restrict__ row_token,
                                                 int* __restrict__ tok_pos) {
    int i = blockIdx.x * 256 + threadIdx.x;  // slot index
    int pos = ebase[tok_e[i]] + rank[i];
    row_token[pos] = i >> 1;
    tok_pos[i] = pos;
}

// ---------------- GEMM1: h = silu(x@Wg) * (x@Wu), grouped by expert ----------
// BK=32, global_load_lds, row-paired 128 B LDS lines (0-conflict, r10-verified)
__global__ __launch_bounds__(256, 4) void gemm1_k(const ushort* __restrict__ x,
                                                  const ushort* __restrict__ wgu_t,
                                                  const int* __restrict__ ebase,
                                                  const int* __restrict__ row_token,
                                                  ushort* __restrict__ h) {
    int e = blockIdx.z;
    int base = ebase[e];
    int cnt = ebase[e + 1] - base;
    int tile0 = blockIdx.y * 128;
    if (tile0 >= cnt) return;
    int c0 = blockIdx.x * 64;            // h-col tile (64 cols)

    __shared__ ushort smem[128 * 32 + 128 * 32];  // 16 KB: A | B(64 gate+64 up)
    ushort* lds_a = smem;
    ushort* lds_b = smem + 128 * 32;

    int tid = threadIdx.x;
    int lane = tid & 63, wv = tid >> 6;
    int wr = wv >> 1, wc = wv & 1;

    const ushort* asrc[2];
    const ushort* bsrc[2];
#pragma unroll
    for (int i = 0; i < 2; ++i) {
        int c = tid + i * 256;
        int rp = c >> 3, s = c & 7;
        int lp = s ^ (rp & 7);
        int row = 2 * rp + (lp >> 2);            // 0..127
        int q = lp & 3;
        int r = tile0 + row;
        r = (r < cnt) ? r : (cnt - 1);
        int tok = row_token[base + r];
        asrc[i] = x + (size_t)tok * D_DIM + q * 8;
        int gc = (row < 64) ? (c0 + row) : (F_DIM + c0 + row - 64);
        bsrc[i] = wgu_t + ((size_t)e * (2 * F_DIM) + gc) * D_DIM + q * 8;
    }

    f32x4 accg[4][2], accu[4][2];
#pragma unroll
    for (int a = 0; a < 4; ++a)
#pragma unroll
        for (int b = 0; b < 2; ++b) {
            accg[a][b] = (f32x4){0.f, 0.f, 0.f, 0.f};
            accu[a][b] = (f32x4){0.f, 0.f, 0.f, 0.f};
        }

    int q = lane >> 4, m = lane & 15;
    int mh = m >> 1;
    int sl = (4 * (m & 1) + q) ^ (mh & 7);       // phys slot, lane-only
    int soff = sl * 8;

    for (int k0 = 0; k0 < D_DIM; k0 += 32) {
        __syncthreads();
#pragma unroll
        for (int i = 0; i < 2; ++i) {
            int c = tid + i * 256;
            gload16(asrc[i] + k0, lds_a + (size_t)c * 8);
            gload16(bsrc[i] + k0, lds_b + (size_t)c * 8);
        }
        __syncthreads();   // vmcnt(0) drain -> LDS populated

        bf16x8 af[4], bg[2], bu[2];
#pragma unroll
        for (int mt = 0; mt < 4; ++mt)
            af[mt] = *(const bf16x8*)(lds_a + (wr * 32 + mt * 8 + mh) * 64 + soff);
#pragma unroll
        for (int nt = 0; nt < 2; ++nt) {
            bg[nt] = *(const bf16x8*)(lds_b + (wc * 16 + nt * 8 + mh) * 64 + soff);
            bu[nt] = *(const bf16x8*)(lds_b + (32 + wc * 16 + nt * 8 + mh) * 64 + soff);
        }
#pragma unroll
        for (int mt = 0; mt < 4; ++mt)
#pragma unroll
            for (int nt = 0; nt < 2; ++nt) {
                accg[mt][nt] = __builtin_amdgcn_mfma_f32_16x16x32_bf16(af[mt], bg[nt], accg[mt][nt], 0, 0, 0);
                accu[mt][nt] = __builtin_amdgcn_mfma_f32_16x16x32_bf16(af[mt], bu[nt], accu[mt][nt], 0, 0, 0);
            }
    }

    // ---- epilogue: silu*up -> LDS stage [32][68] -> coalesced 16B stores ----
    ushort* stg = smem;
    int col = m;
    __syncthreads();
#pragma unroll
    for (int mt = 0; mt < 4; ++mt) {
#pragma unroll
        for (int nt = 0; nt < 2; ++nt) {
            int sc = wc * 32 + nt * 16 + col;
#pragma unroll
            for (int r4 = 0; r4 < 4; ++r4) {
                int sr = wr * 16 + q * 4 + r4;
                float g = accg[mt][nt][r4];
                float u = accu[mt][nt][r4];
                stg[sr * 68 + sc] = f2b((g / (1.f + __expf(-g))) * u);
            }
        }
        __syncthreads();
        {
            int sr = tid >> 3;
            int coff = (tid & 7) * 8;
            int grow = tile0 + (sr >> 4) * 64 + mt * 16 + (sr & 15);
            if (grow < cnt)
                *(uint4*)(h + (size_t)(base + grow) * F_DIM + c0 + coff) =
                    *(const uint4*)(stg + sr * 68 + coff);
        }
        __syncthreads();
    }
}

// -------- GEMM2: slot = h @ Wd (bf16); BK=32, row-paired swizzled lines -----
__global__ __launch_bounds__(256, 4) void gemm2_k(const ushort* __restrict__ h,
                                                  const ushort* __restrict__ wd_t,
                                                  const int* __restrict__ ebase,
                                                  ushort* __restrict__ slot) {
    int e = blockIdx.z;
    int base = ebase[e];
    int cnt = ebase[e + 1] - base;
    int tile0 = blockIdx.y * 128;
    if (tile0 >= cnt) return;
    int c0 = blockIdx.x * 128;

    __shared__ ushort smem[128 * 32 + 128 * 32];  // 16 KB
    ushort* lds_a = smem;
    ushort* lds_b = smem + 128 * 32;

    int tid = threadIdx.x;
    int lane = tid & 63, wv = tid >> 6;
    int wr = wv >> 1, wc = wv & 1;

    const ushort* asrc[2]; const ushort* bsrc[2];
#pragma unroll
    for (int i = 0; i < 2; ++i) {
        int c = tid + i * 256;
        int rp = c >> 3, s = c & 7;
        int lp = s ^ (rp & 7);
        int row = 2 * rp + (lp >> 2);
        int q = lp & 3;
        int r = tile0 + row;
        r = (r < cnt) ? r : (cnt - 1);
        asrc[i] = h + (size_t)(base + r) * F_DIM + q * 8;
        bsrc[i] = wd_t + ((size_t)e * D_DIM + c0 + row) * F_DIM + q * 8;
    }

    f32x4 acc[4][4];
#pragma unroll
    for (int a = 0; a < 4; ++a)
#pragma unroll
        for (int b = 0; b < 4; ++b) acc[a][b] = (f32x4){0.f, 0.f, 0.f, 0.f};

    int q = lane >> 4, m = lane & 15;
    int mh = m >> 1;
    int sl = (4 * (m & 1) + q) ^ (mh & 7);
    int soff = sl * 8;

    for (int k0 = 0; k0 < F_DIM; k0 += 32) {
        __syncthreads();
#pragma unroll
        for (int i = 0; i < 2; ++i) {
            int c = tid + i * 256;
            gload16(asrc[i] + k0, lds_a + (size_t)c * 8);
            gload16(bsrc[i] + k0, lds_b + (size_t)c * 8);
        }
        __syncthreads();

        bf16x8 af[4], bb[4];
#pragma unroll
        for (int mt = 0; mt < 4; ++mt)
            af[mt] = *(const bf16x8*)(lds_a + (wr * 32 + mt * 8 + mh) * 64 + soff);
#pragma unroll
        for (int nt = 0; nt < 4; ++nt)
            bb[nt] = *(const bf16x8*)(lds_b + (wc * 32 + nt * 8 + mh) * 64 + soff);
#pragma unroll
        for (int mt = 0; mt < 4; ++mt)
#pragma unroll
            for (int nt = 0; nt < 4; ++nt)
                acc[mt][nt] = __builtin_amdgcn_mfma_f32_16x16x32_bf16(af[mt], bb[nt], acc[mt][nt], 0, 0, 0);
    }

    // epilogue: stage [32][132] -> coalesced bf16 slot rows
    ushort* stg = smem;
    int col = m;
    __syncthreads();
#pragma unroll
    for (int mt = 0; mt < 4; ++mt) {
#pragma unroll
        for (int nt = 0; nt < 4; ++nt) {
            int scol = wc * 64 + nt * 16 + col;
#pragma unroll
            for (int r4 = 0; r4 < 4; ++r4) {
                int sr = wr * 16 + q * 4 + r4;
                stg[sr * 132 + scol] = f2b(acc[mt][nt][r4]);
            }
        }
        __syncthreads();
#pragma unroll
        for (int i = 0; i < 2; ++i) {
            int c = tid + i * 256;
            int sr = c >> 4;
            int coff = (c & 15) * 8;
            int grow = tile0 + (sr >> 4) * 64 + mt * 16 + (sr & 15);
            if (grow < cnt)
                *(uint4*)(slot + (size_t)(base + grow) * D_DIM + c0 + coff) =
                    *(const uint4*)(stg + sr * 132 + coff);
        }
        __syncthreads();
    }
}

// ------ combine: out[t] = w0*slot[p0] + w1*slot[p1]  (wave per token) -------
__global__ __launch_bounds__(256) void combine_k(const ushort* __restrict__ slot,
                                                 const int* __restrict__ tok_pos,
                                                 const float* __restrict__ tok_w,
                                                 float* __restrict__ out) {
    int lane = threadIdx.x & 63, wv = threadIdx.x >> 6;
    int t = blockIdx.x * 4 + wv;
    int p0 = tok_pos[2 * t], p1 = tok_pos[2 * t + 1];
    float w0 = tok_w[2 * t], w1 = tok_w[2 * t + 1];
    uint4 s0 = *(const uint4*)(slot + (size_t)p0 * D_DIM + lane * 8);
    uint4 s1 = *(const uint4*)(slot + (size_t)p1 * D_DIM + lane * 8);
    const ushort* a = (const ushort*)&s0;
    const ushort* b = (const ushort*)&s1;
    float o[8];
#pragma unroll
    for (int j = 0; j < 8; ++j) o[j] = w0 * b2f(a[j]) + w1 * b2f(b[j]);
    float* dst = out + (size_t)t * D_DIM + lane * 8;
    *(float4*)dst = (float4){o[0], o[1], o[2], o[3]};
    *(float4*)(dst + 4) = (float4){o[4], o[5], o[6], o[7]};
}

extern "C" void kernel_launch(void* const* d_in, const int* in_sizes, int n_in,
                              void* d_out, int out_size, void* d_ws, size_t ws_size,
                              hipStream_t stream) {
    const float* x   = (const float*)d_in[0];
    const float* rw  = (const float*)d_in[1];
    const float* rb  = (const float*)d_in[2];
    const float* wgu = (const float*)d_in[3];
    const float* wd  = (const float*)d_in[4];
    float* out = (float*)d_out;

    char* ws = (char*)d_ws;
    size_t off = 0;
    auto alloc = [&](size_t bytes) -> void* {
        void* p = ws + off;
        off += (bytes + 255) & ~(size_t)255;
        return p;
    };
    ushort* wgu_t     = (ushort*)alloc((size_t)E_NUM * 2 * F_DIM * D_DIM * 2);  // 16.8 MB
    ushort* wd_t      = (ushort*)alloc((size_t)E_NUM * D_DIM * F_DIM * 2);      //  8.4 MB
    ushort* x_bf      = (ushort*)alloc((size_t)N_TOK * D_DIM * 2);              //  8.4 MB
    ushort* hbuf      = (ushort*)alloc((size_t)M_SLOTS * F_DIM * 2);            // 33.6 MB
    ushort* slot      = (ushort*)alloc((size_t)M_SLOTS * D_DIM * 2);            // 16.8 MB
    int*    row_token = (int*)alloc(M_SLOTS * 4);
    int*    tok_e     = (int*)alloc(M_SLOTS * 4);
    int*    rankbuf   = (int*)alloc(M_SLOTS * 4);
    float*  tok_w     = (float*)alloc(M_SLOTS * 4);
    int*    tok_pos   = (int*)alloc(M_SLOTS * 4);
    int*    cnt       = (int*)alloc(64);
    int*    ebase     = (int*)alloc(64);

    logits_k<<<N_TOK / 4, 256, 0, stream>>>(x, rw, rb, x_bf, tok_e, tok_w, cnt);
    transpose_k<<<dim3(2 * F_DIM / 64, D_DIM / 64, E_NUM), 256, 0, stream>>>(wgu, wgu_t, D_DIM, 2 * F_DIM);
    transpose_k<<<dim3(D_DIM / 64, F_DIM / 64, E_NUM), 256, 0, stream>>>(wd, wd_t, F_DIM, D_DIM);
    assign_k<<<M_SLOTS / 256, 256, 0, stream>>>(tok_e, cnt, rankbuf);
    prefix_k<<<1, 64, 0, stream>>>(cnt, ebase);
    scatter_k<<<M_SLOTS / 256, 256, 0, stream>>>(tok_e, rankbuf, ebase, row_token, tok_pos);
    gemm1_k<<<dim3(16, 32, E_NUM), 256, 0, stream>>>(x_bf, wgu_t, ebase, row_token, hbuf);
    gemm2_k<<<dim3(4, 32, E_NUM), 256, 0, stream>>>(hbuf, wd_t, ebase, slot);
    combine_k<<<N_TOK / 4, 256, 0, stream>>>(slot, tok_pos, tok_w, out);
}